// Round 1
// 209.541 us; speedup vs baseline: 1.0025x; 1.0025x over previous
//
#include <hip/hip_runtime.h>

// SoftPool 2d: x(32,128,128,64) fp32, 2x2/stride2 windows.
// Per pixel: h = tanh(x @ We + be)  (64->128), logit = sigmoid(h @ Wr + br).
// Per window: softmax over 4 logits, out = sum_e w_e * x_e  (fp32 blend).
// One wave = 16 pixels = 4 windows; mfma_f32_16x16x32_bf16, N=128 (8 tiles), K=64 (2 steps).
// R6: exact-resident grid (1024 blocks = 4/CU), L_=8 iters/wave, no LDS.
// R7: in-register blend + depth-2 prefetch.
//     - Dropped the second read of x (x0..x3/nx0..nx3): blend directly from
//       the fp32 A-values already in registers. Weight transpose
//       (window-row -> pixel-lane) via one ds_bpermute + 3 selects; sum over
//       the 4 elem-lanes via DPP quad_perm butterflies. Same store coverage
//       (1 KiB/wave contiguous), -4 loads/iter, -32 VGPRs of pipeline state.
//     - Freed regs fund a 3-stage depth-2 prefetch of the A loads: 8 KiB
//       distinct HBM misses in flight per wave (was 4 KiB; x-loads were
//       L2-merged duplicates). Theory: HBM-latency-bound at the hard
//       4-waves/SIMD occupancy cap (Bf alone is 64 VGPRs).
//     - Full unroll (L_=8) keeps stage indices compile-time (no scratch).

typedef __attribute__((ext_vector_type(8))) short short8;    // 8 bf16 = 4 VGPRs
typedef __attribute__((ext_vector_type(4))) float floatx4;

#define B_   32
#define R_   128
#define C_   128
#define D_   64
#define H_   128
#define NW_  (B_ * 64 * 64)     // 131072 windows
#define NGRP_ (NW_ / 4)         // 32768 groups of 4 windows
#define NBLK_ 1024              // 4 blocks/CU -> all resident, zero churn
#define NWAVE_ (NBLK_ * 4)      // 4096 waves
#define L_   (NGRP_ / NWAVE_)   // 8 iters per wave

#define XSTEP_ (4L * R_ * C_ * D_)       // +4 images per iter (in floats)
#define OSTEP_ ((long)NWAVE_ * 4 * 64)   // +16384 windows * 64 ch per iter

#define L2E_  1.4426950408889634f   // log2(e)
#define T2L_  2.8853900817779268f   // 2*log2(e)

__device__ __forceinline__ unsigned short f2bf_rne(float f) {
  union { float f; unsigned int u; } v; v.f = f;
  unsigned int u = v.u;
  u += 0x7fffu + ((u >> 16) & 1u);
  return (unsigned short)(u >> 16);
}

// pack 2 floats -> 2 bf16 via v_perm (round-half-up), 3 VALU ops (verified R4)
__device__ __forceinline__ unsigned int pk_bf16(float lo, float hi) {
  unsigned int a = __builtin_bit_cast(unsigned int, lo) + 0x8000u;
  unsigned int b = __builtin_bit_cast(unsigned int, hi) + 0x8000u;
  return __builtin_amdgcn_perm(b, a, 0x07060302u);
}

// x += value from lane (lane ^ mask) within the DPP pattern, VALU-rate.
template <int CTRL>
__device__ __forceinline__ float dpp_add(float x) {
  int xi = __builtin_bit_cast(int, x);
  int yi = __builtin_amdgcn_update_dpp(0, xi, CTRL, 0xf, 0xf, true);
  return x + __builtin_bit_cast(float, yi);
}
#define DPP_XOR1   0xB1    // quad_perm [1,0,3,2]
#define DPP_XOR2   0x4E    // quad_perm [2,3,0,1]
#define DPP_XOR3   0x1B    // quad_perm [3,2,1,0]
#define DPP_XOR7   0x141   // row_half_mirror
#define DPP_XOR15  0x140   // row_mirror
// masks {1,3,7,15} linearly independent over GF(2)^4 -> full 16-lane sum
__device__ __forceinline__ float row_reduce16(float x) {
  x = dpp_add<DPP_XOR1>(x);
  x = dpp_add<DPP_XOR3>(x);
  x = dpp_add<DPP_XOR7>(x);
  x = dpp_add<DPP_XOR15>(x);
  return x;
}
// sum across each aligned 4-lane quad (butterfly over masks {1,2})
__device__ __forceinline__ float quad_sum(float x) {
  x = dpp_add<DPP_XOR1>(x);
  x = dpp_add<DPP_XOR2>(x);
  return x;
}

// ---- prep: B-fragments in per-lane order into d_ws (verified R5) ----
// F[fi=n*2+ks][lane=quad*16+c][j=0..7] = bf16( We[(ks*32+quad*8+j)*128 + n*16+c] )
__global__ void prep_kernel(const float* __restrict__ We,
                            unsigned short* __restrict__ F)
{
  int t = blockIdx.x * 256 + threadIdx.x;   // 8192 threads, one element each
  int j    = t & 7;
  int lane = (t >> 3) & 63;
  int fi   = t >> 9;
  int n  = fi >> 1, ks = fi & 1;
  int quad = lane >> 4, c = lane & 15;
  F[t] = f2bf_rne(We[(ks * 32 + quad * 8 + j) * 128 + n * 16 + c]);
}

__global__ __launch_bounds__(256, 2) void softpool_kernel(
    const float* __restrict__ x, const unsigned short* __restrict__ F,
    const float* __restrict__ be, const float* __restrict__ Wr,
    const float* __restrict__ br, float* __restrict__ out)
{
  const int lane = threadIdx.x & 63;
  const int wv   = threadIdx.x >> 6;
  const int c    = lane & 15;   // A row (pixel-in-tile) / C col
  const int quad = lane >> 4;   // k-quad for A/B; channel-chunk for blend

  // ---- once-per-wave setup, amortized over L_=8 iters ----
  short8 Bf[8][2];
#pragma unroll
  for (int n = 0; n < 8; ++n)
#pragma unroll
    for (int ks = 0; ks < 2; ++ks)
      Bf[n][ks] = *(const short8*)&F[((n * 2 + ks) * 64 + lane) * 8];

  // epilogue constants: beK = be*2log2(e), wr2 = -2*Wr, swr = sum_n Wr
  float beK[8], wr2[8], swr = 0.f;
#pragma unroll
  for (int n = 0; n < 8; ++n) {
    float w = Wr[n * 16 + c];
    beK[n] = be[n * 16 + c] * T2L_;
    wr2[n] = -2.0f * w;
    swr += w;
  }
  const float brN = -L2E_ * br[0];

  const int gw = blockIdx.x * 4 + wv;     // iter-0 group; +4096 groups/iter

  // ---- A-load addressing (iter 0; advances by +4 images/iter) ----
  const int w0   = gw * 4 + (c >> 2);     // window of pixel p=c
  const int elem = c & 3;                 // elem = si*2+sj
  const int bb = w0 >> 12;
  const int qq = (w0 >> 6) & 63;
  const int pp = w0 & 63;
  const float* xp = x + (((bb * R_ + (qq * 2 + (elem >> 1))) * C_
                          + (pp * 2 + (elem & 1))) * D_) + quad * 8;

  // ---- store base: lane (quad,c) stores window (c>>2), chunk picked by elem
  // e=0 -> ch [8q,8q+4), e=1 -> [8q+4,8q+8), e=2 -> [8q+32,8q+36), e=3 -> [8q+36,8q+40)
  const int win = c >> 2;
  float* op = out + (long)(gw * 4 + win) * 64
            + quad * 8 + ((elem & 1) << 2) + ((elem & 2) << 4);

  // weight transpose: read w[win][elem] from row `win`, lane `elem`
  const int  widx = (win * 16 + elem) << 2;   // ds_bpermute byte index
  const bool oddc = (c & 1) != 0;             // = elem&1
  const bool hi2c = (c & 2) != 0;             // = elem&2

  // ---- 3-stage / depth-2 pipeline of A loads (16 fp32 per stage) ----
  floatx4 st[3][4];
#pragma unroll
  for (int s = 0; s < 2; ++s) {
    const float* p = xp + (long)s * XSTEP_;
    st[s][0] = *(const floatx4*)(p);
    st[s][1] = *(const floatx4*)(p + 4);
    st[s][2] = *(const floatx4*)(p + 32);
    st[s][3] = *(const floatx4*)(p + 36);
  }

#pragma unroll
  for (int it = 0; it < L_; ++it) {
    // ---- prefetch iter it+2 (skipped for the last two iters) ----
    if (it < L_ - 2) {
      const int ps = (it + 2) % 3;   // stage freed by iter it-1's blend
      const float* p = xp + 2 * XSTEP_;
      st[ps][0] = *(const floatx4*)(p);
      st[ps][1] = *(const floatx4*)(p + 4);
      st[ps][2] = *(const floatx4*)(p + 32);
      st[ps][3] = *(const floatx4*)(p + 36);
    }

    const int cs = it % 3;
    const floatx4 a0 = st[cs][0], a1 = st[cs][1];
    const floatx4 a2 = st[cs][2], a3 = st[cs][3];

    // ---- bf16 A fragments (perm-packed converts) ----
    union { unsigned int u[4]; short8 v; } A0u, A1u;
    A0u.u[0] = pk_bf16(a0[0], a0[1]); A0u.u[1] = pk_bf16(a0[2], a0[3]);
    A0u.u[2] = pk_bf16(a1[0], a1[1]); A0u.u[3] = pk_bf16(a1[2], a1[3]);
    A1u.u[0] = pk_bf16(a2[0], a2[1]); A1u.u[1] = pk_bf16(a2[2], a2[3]);
    A1u.u[2] = pk_bf16(a3[0], a3[1]); A1u.u[3] = pk_bf16(a3[2], a3[3]);

    // ---- 16 MFMAs: h for 16 pixels x 128 hidden ----
    floatx4 acc[8];
#pragma unroll
    for (int n = 0; n < 8; ++n) {
      floatx4 z = {0.f, 0.f, 0.f, 0.f};
      z = __builtin_amdgcn_mfma_f32_16x16x32_bf16(A0u.v, Bf[n][0], z, 0, 0, 0);
      acc[n] = __builtin_amdgcn_mfma_f32_16x16x32_bf16(A1u.v, Bf[n][1], z, 0, 0, 0);
    }

    // ---- tanh-dot, rcp form: p = swr + sum_n (-2wr_n)*rcp(1+exp2(2L*(acc+be))) ----
    float p0 = swr, p1 = swr, p2 = swr, p3 = swr;
#pragma unroll
    for (int n = 0; n < 8; ++n) {
      float e0 = __builtin_amdgcn_exp2f(fmaf(acc[n][0], T2L_, beK[n]));
      float e1 = __builtin_amdgcn_exp2f(fmaf(acc[n][1], T2L_, beK[n]));
      float e2 = __builtin_amdgcn_exp2f(fmaf(acc[n][2], T2L_, beK[n]));
      float e3 = __builtin_amdgcn_exp2f(fmaf(acc[n][3], T2L_, beK[n]));
      p0 = fmaf(wr2[n], __builtin_amdgcn_rcpf(e0 + 1.0f), p0);
      p1 = fmaf(wr2[n], __builtin_amdgcn_rcpf(e1 + 1.0f), p1);
      p2 = fmaf(wr2[n], __builtin_amdgcn_rcpf(e2 + 1.0f), p2);
      p3 = fmaf(wr2[n], __builtin_amdgcn_rcpf(e3 + 1.0f), p3);
    }
    // reduce over the 16 lanes of this quad's DPP row, VALU-rate
    p0 = row_reduce16(p0);
    p1 = row_reduce16(p1);
    p2 = row_reduce16(p2);
    p3 = row_reduce16(p3);
    // sigmoid (rcp form); logits bounded [0,1] so softmax needs no max-subtract
    float l0 = __builtin_amdgcn_rcpf(1.0f + __builtin_amdgcn_exp2f(fmaf(p0, -L2E_, brN)));
    float l1 = __builtin_amdgcn_rcpf(1.0f + __builtin_amdgcn_exp2f(fmaf(p1, -L2E_, brN)));
    float l2 = __builtin_amdgcn_rcpf(1.0f + __builtin_amdgcn_exp2f(fmaf(p2, -L2E_, brN)));
    float l3 = __builtin_amdgcn_rcpf(1.0f + __builtin_amdgcn_exp2f(fmaf(p3, -L2E_, brN)));
    float s0 = __builtin_amdgcn_exp2f(l0 * L2E_);
    float s1 = __builtin_amdgcn_exp2f(l1 * L2E_);
    float s2 = __builtin_amdgcn_exp2f(l2 * L2E_);
    float s3 = __builtin_amdgcn_exp2f(l3 * L2E_);
    float inv = __builtin_amdgcn_rcpf(s0 + s1 + s2 + s3);
    float w0f = s0 * inv, w1f = s1 * inv, w2f = s2 * inv, w3f = s3 * inv;
    // row q now holds window q's 4 softmax weights (uniform across its 16 lanes)

    // ---- weight transpose: this lane (pixel c = window win, elem) needs
    //      w[win][elem], held by row `win`. Select w_{c&3} locally, then one
    //      full-wave ds_bpermute from lane (win*16 + elem).
    float wa = oddc ? w1f : w0f;
    float wb = oddc ? w3f : w2f;
    float wsel = hi2c ? wb : wa;
    float W = __builtin_bit_cast(float,
        __builtin_amdgcn_ds_bpermute(widx, __builtin_bit_cast(int, wsel)));

    // ---- in-register blend: weighted quad-sum of the fp32 A-values ----
    // lanes (q, 4*win+e), e=0..3 hold the 4 pixels of window `win` at the
    // same 16 channels -> sum over the aligned 4-lane quad.
    floatx4 t0 = a0 * W, t1 = a1 * W, t2 = a2 * W, t3 = a3 * W;
    floatx4 o0, o1, o2, o3;
#pragma unroll
    for (int j = 0; j < 4; ++j) {
      o0[j] = quad_sum(t0[j]);
      o1[j] = quad_sum(t1[j]);
      o2[j] = quad_sum(t2[j]);
      o3[j] = quad_sum(t3[j]);
    }
    // each lane stores the chunk matching its elem (wave covers 1 KiB contig)
    floatx4 o = hi2c ? (oddc ? o3 : o2) : (oddc ? o1 : o0);
    *(floatx4*)(op) = o;

    xp += XSTEP_;
    op += OSTEP_;
  }
}

extern "C" void kernel_launch(void* const* d_in, const int* in_sizes, int n_in,
                              void* d_out, int out_size, void* d_ws, size_t ws_size,
                              hipStream_t stream) {
  const float* x  = (const float*)d_in[0];
  const float* We = (const float*)d_in[1];
  const float* be = (const float*)d_in[2];
  const float* Wr = (const float*)d_in[3];
  const float* br = (const float*)d_in[4];
  float* out = (float*)d_out;
  unsigned short* F = (unsigned short*)d_ws;   // 16 KB of fragment data

  prep_kernel<<<32, 256, 0, stream>>>(We, F);
  softpool_kernel<<<NBLK_, 256, 0, stream>>>(x, F, be, Wr, br, out);
}